// Round 5
// baseline (853.603 us; speedup 1.0000x reference)
//
#include <hip/hip_runtime.h>
#include <hip/hip_bf16.h>
#include <stdint.h>

// Problem constants
constexpr int Bb = 2;
constexpr int Ll = 2048;
constexpr int Dd = 1024;
constexpr int Nn = 16;
constexpr int NB = Dd * Nn;    // 16384 (B or C out-features)
constexpr int NB2 = 2 * NB;    // 32768 (merged BC out-features)
constexpr int SL = 64;         // scan segment length
constexpr int NCH = Bb * Dd;   // 2048 channels
constexpr int KCAT = 3 * Dd;   // 3072: [u_hi|u_lo|u_hi] x [W_hi|W_hi|W_lo]

typedef __bf16 bf16_t;
typedef __bf16 bf16x8 __attribute__((ext_vector_type(8)));
typedef __bf16 bf16x4 __attribute__((ext_vector_type(4)));
typedef float f32x4 __attribute__((ext_vector_type(4)));

// async global->LDS, 16 B per lane. HW LDS dest = wave-uniform base + lane*16;
// passing per-lane ptr base+tid*16 matches that exactly (m97/m104 pattern).
__device__ inline void gld_lds16(const void* g, void* l) {
    __builtin_amdgcn_global_load_lds(
        (const __attribute__((address_space(1))) unsigned int*)g,
        (__attribute__((address_space(3))) unsigned int*)l, 16, 0, 0);
}

// ---------- prep: u -> u_bf (bf16) and u_cat ([hi|lo|hi], K=3072) ----------
__global__ __launch_bounds__(256) void build_ucat(const float* __restrict__ u,
                                                  bf16_t* __restrict__ ucat,
                                                  bf16_t* __restrict__ ubf) {
    const int i = blockIdx.x * 256 + threadIdx.x;   // one float4, 4096*256 total
    const int row = i >> 8;
    const int c = (i & 255) << 2;
    float4 v = ((const float4*)u)[i];
    bf16x4 hi = {(bf16_t)v.x, (bf16_t)v.y, (bf16_t)v.z, (bf16_t)v.w};
    bf16x4 lo = {(bf16_t)(v.x - (float)hi.x), (bf16_t)(v.y - (float)hi.y),
                 (bf16_t)(v.z - (float)hi.z), (bf16_t)(v.w - (float)hi.w)};
    bf16_t* r = ucat + (size_t)row * KCAT;
    *(bf16x4*)(r + c) = hi;
    *(bf16x4*)(r + Dd + c) = lo;
    *(bf16x4*)(r + 2 * Dd + c) = hi;
    *(bf16x4*)(ubf + (size_t)i * 4) = hi;
}

// W_cat row = [W_hi | W_hi | W_lo]
__global__ __launch_bounds__(256) void build_wcat(const float* __restrict__ w,
                                                  bf16_t* __restrict__ wcat) {
    const int i = blockIdx.x * 256 + threadIdx.x;   // 1024*256 total
    const int row = i >> 8;
    const int c = (i & 255) << 2;
    float4 v = ((const float4*)w)[i];
    bf16x4 hi = {(bf16_t)v.x, (bf16_t)v.y, (bf16_t)v.z, (bf16_t)v.w};
    bf16x4 lo = {(bf16_t)(v.x - (float)hi.x), (bf16_t)(v.y - (float)hi.y),
                 (bf16_t)(v.z - (float)hi.z), (bf16_t)(v.w - (float)hi.w)};
    bf16_t* r = wcat + (size_t)row * KCAT;
    *(bf16x4*)(r + c) = hi;
    *(bf16x4*)(r + Dd + c) = hi;
    *(bf16x4*)(r + 2 * Dd + c) = lo;
}

// [W_B ; W_C] -> contiguous bf16 wBC (rows 0..NB-1 = W_B, NB.. = W_C)
__global__ __launch_bounds__(256) void cvt_wbc(const float* __restrict__ wB,
                                               const float* __restrict__ wC,
                                               bf16_t* __restrict__ d) {
    const int half = NB * Dd / 4;                   // float4 count per matrix
    int i = blockIdx.x * 256 + threadIdx.x;
    const int stride = gridDim.x * 256;
    for (; i < 2 * half; i += stride) {
        float4 v = (i < half) ? ((const float4*)wB)[i]
                              : ((const float4*)wC)[i - half];
        bf16x4 o = {(bf16_t)v.x, (bf16_t)v.y, (bf16_t)v.z, (bf16_t)v.w};
        *(bf16x4*)(d + (size_t)i * 4) = o;
    }
}

// ---------- merged B/C projection GEMM (m97 staging, 128x128 tile) ----------
// C[2*CL, NB2] = u_bf @ wBC^T + bias(col<NB ? b_B : b_C), output bf16.
// Row rglob -> u row (rglob/CL)*Ll + l0 + rglob%CL  (CL%128==0, no straddle).
__global__ __launch_bounds__(256) void gemm_bc(
    const bf16_t* __restrict__ Abase, int CL, int l0,
    const bf16_t* __restrict__ W, const float* __restrict__ bB,
    const float* __restrict__ bC, bf16_t* __restrict__ C)
{
    constexpr int K = Dd;
    __shared__ bf16_t As[128 * 32];
    __shared__ bf16_t Bs[128 * 32];

    const int tid = threadIdx.x;
    const int bn = blockIdx.x * 128;
    const int rglob = blockIdx.y * 128;
    const int batch = rglob / CL;
    const int rin = rglob % CL;
    const bf16_t* Ap = Abase + ((size_t)batch * Ll + l0 + rin) * K;
    const bf16_t* Wp = W + (size_t)bn * K;
    bf16_t* Cp = C + (size_t)rglob * NB2;

    const int sr = tid >> 2;          // staging row 0..63
    const int sc = (tid & 3) << 3;    // staging k offset (bf16 elems)
    char* ldsA = (char*)As + tid * 16;   // row sr, chunk sc -> byte tid*16
    char* ldsB = (char*)Bs + tid * 16;

    const int lane = tid & 63;
    const int wid = tid >> 6;
    const int wm = (wid & 1) << 6;
    const int wn = (wid >> 1) << 6;
    const int lr = lane & 15;
    const int lq = lane >> 4;

    f32x4 acc[4][4] = {};

    for (int k0 = 0; k0 < K; k0 += 32) {
        __syncthreads();   // prior iteration's LDS reads done
        gld_lds16(Ap + (size_t)sr * K + k0 + sc, ldsA);
        gld_lds16(Ap + (size_t)(sr + 64) * K + k0 + sc, ldsA + 4096);
        gld_lds16(Wp + (size_t)sr * K + k0 + sc, ldsB);
        gld_lds16(Wp + (size_t)(sr + 64) * K + k0 + sc, ldsB + 4096);
        __syncthreads();   // compiler drains vmcnt before barrier

        bf16x8 af[4], bfr[4];
#pragma unroll
        for (int mi = 0; mi < 4; ++mi)
            af[mi] = *(const bf16x8*)&As[(wm + mi * 16 + lr) * 32 + lq * 8];
#pragma unroll
        for (int ni = 0; ni < 4; ++ni)
            bfr[ni] = *(const bf16x8*)&Bs[(wn + ni * 16 + lr) * 32 + lq * 8];
#pragma unroll
        for (int mi = 0; mi < 4; ++mi)
#pragma unroll
            for (int ni = 0; ni < 4; ++ni)
                acc[mi][ni] = __builtin_amdgcn_mfma_f32_16x16x32_bf16(
                    af[mi], bfr[ni], acc[mi][ni], 0, 0, 0);
    }

    // C/D layout: col=lane&15, row=(lane>>4)*4+i (m89/m91-verified)
#pragma unroll
    for (int ni = 0; ni < 4; ++ni) {
        const int col = bn + wn + ni * 16 + lr;
        const float bc = (col < NB) ? bB[col] : bC[col - NB];  // block-uniform side
#pragma unroll
        for (int mi = 0; mi < 4; ++mi)
#pragma unroll
            for (int i = 0; i < 4; ++i)
                Cp[(size_t)(wm + mi * 16 + lq * 4 + i) * NB2 + col] =
                    (bf16_t)(acc[mi][ni][i] + bc);
    }
}

// ---------- dt GEMM: 64x64 tile, 1024 blocks (~4/CU) for barrier overlap ----
// dt[4096, 1024] = softplus(ucat @ wcat^T + b_dt + dt_bias); hi/lo split gives
// fp32-grade logits. Each of 4 waves computes one 16x64 strip (4 MFMAs/iter).
__global__ __launch_bounds__(256) void gemm_dt64(
    const bf16_t* __restrict__ ucat, const bf16_t* __restrict__ wcat,
    const float* __restrict__ b1, const float* __restrict__ b2,
    float* __restrict__ dt)
{
    constexpr int K = KCAT;
    __shared__ bf16_t As[64 * 32];
    __shared__ bf16_t Bs[64 * 32];

    const int tid = threadIdx.x;
    const int bn = blockIdx.x * 64;
    const int bm = blockIdx.y * 64;
    const bf16_t* Ap = ucat + (size_t)bm * K;
    const bf16_t* Wp = wcat + (size_t)bn * K;

    const int sr = tid >> 2;
    const int sc = (tid & 3) << 3;
    char* ldsA = (char*)As + tid * 16;
    char* ldsB = (char*)Bs + tid * 16;

    const int lane = tid & 63;
    const int w = tid >> 6;          // wave -> rows [w*16, w*16+16)
    const int lr = lane & 15;
    const int lq = lane >> 4;

    f32x4 acc[4] = {};

    for (int k0 = 0; k0 < K; k0 += 32) {
        __syncthreads();
        gld_lds16(Ap + (size_t)sr * K + k0 + sc, ldsA);
        gld_lds16(Wp + (size_t)sr * K + k0 + sc, ldsB);
        __syncthreads();

        const bf16x8 af = *(const bf16x8*)&As[(w * 16 + lr) * 32 + lq * 8];
#pragma unroll
        for (int ni = 0; ni < 4; ++ni) {
            const bf16x8 bf = *(const bf16x8*)&Bs[(ni * 16 + lr) * 32 + lq * 8];
            acc[ni] = __builtin_amdgcn_mfma_f32_16x16x32_bf16(af, bf, acc[ni], 0, 0, 0);
        }
    }

#pragma unroll
    for (int ni = 0; ni < 4; ++ni) {
        const int col = bn + ni * 16 + lr;
        const float bc = b1[col] + b2[col];
#pragma unroll
        for (int i = 0; i < 4; ++i) {
            const int row = bm + w * 16 + lq * 4 + i;
            float v = acc[ni][i] + bc;
            v = (v > 20.f) ? v : log1pf(__expf(v));
            dt[(size_t)row * Dd + col] = v;
        }
    }
}

// ---------- scan pass A: per-segment local scan (h0 = 0) ----------
// BC chunk layout: [row][NB2], Bt at col d*Nn+n, Ct at +NB.
__global__ __launch_bounds__(256) void scan_seg_local(
    const float* __restrict__ u, const float* __restrict__ dt,
    const bf16_t* __restrict__ BC, const float* __restrict__ log_A,
    float* __restrict__ pseg, float* __restrict__ hseg, int CL, int l0)
{
    const int tid = threadIdx.x;
    const int g = tid >> 4, n = tid & 15;
    const int gid = blockIdx.x * 16 + g;
    const int ch = gid & (NCH - 1);
    const int s = gid >> 11;
    const int b = ch >> 10, d = ch & (Dd - 1);

    const float A = -__expf(log_A[d * Nn + n]);
    const float rA = 1.f / A;

    size_t idx_bn = (size_t)(b * CL + s * SL) * NB2 + d * Nn + n;
    size_t idx_u = ((size_t)b * Ll + l0 + s * SL) * Dd + d;

    float p = 1.f, h = 0.f;
    for (int l = 0; l < SL; ++l) {
        const float dtv = dt[idx_u];
        const float uv = u[idx_u];
        const float bv = (float)BC[idx_bn];
        const float a = __expf(dtv * A);
        p *= a;
        h = a * h + (a - 1.f) * rA * bv * uv;
        idx_bn += NB2; idx_u += Dd;
    }
    const size_t o = ((size_t)s * NCH + ch) * Nn + n;
    pseg[o] = p;
    hseg[o] = h;
}

// ---------- scan pass B: sequential combine across segments ----------
__global__ __launch_bounds__(256) void scan_combine(
    const float* __restrict__ pseg, const float* __restrict__ hseg,
    float* __restrict__ hin_arr, float* __restrict__ h_state,
    int NSEG, int l0)
{
    const int t = blockIdx.x * 256 + threadIdx.x;   // (ch,n), 0..32767
    float hin = (l0 == 0) ? 0.f : h_state[t];
    for (int s = 0; s < NSEG; ++s) {
        const size_t o = (size_t)s * (NCH * Nn) + t;
        hin_arr[o] = hin;
        hin = pseg[o] * hin + hseg[o];
    }
    h_state[t] = hin;
}

// ---------- scan pass C: re-run segment from correct h_in, emit y ----------
__global__ __launch_bounds__(256) void scan_seg_final(
    const float* __restrict__ u, const float* __restrict__ dt,
    const bf16_t* __restrict__ BC, const float* __restrict__ log_A,
    const float* __restrict__ D_skip, const float* __restrict__ hin_arr,
    float* __restrict__ y, int CL, int l0)
{
    const int tid = threadIdx.x;
    const int g = tid >> 4, n = tid & 15;
    const int gid = blockIdx.x * 16 + g;
    const int ch = gid & (NCH - 1);
    const int s = gid >> 11;
    const int b = ch >> 10, d = ch & (Dd - 1);

    const float A = -__expf(log_A[d * Nn + n]);
    const float rA = 1.f / A;
    const float Dsk = D_skip[d];

    size_t idx_bn = (size_t)(b * CL + s * SL) * NB2 + d * Nn + n;
    size_t idx_u = ((size_t)b * Ll + l0 + s * SL) * Dd + d;

    float h = hin_arr[((size_t)s * NCH + ch) * Nn + n];
    for (int l = 0; l < SL; ++l) {
        const float dtv = dt[idx_u];
        const float uv = u[idx_u];
        const float bv = (float)BC[idx_bn];
        const float cv = (float)BC[idx_bn + NB];
        const float a = __expf(dtv * A);
        h = a * h + (a - 1.f) * rA * bv * uv;
        float p = cv * h;
        p += __shfl_xor(p, 1);
        p += __shfl_xor(p, 2);
        p += __shfl_xor(p, 4);
        p += __shfl_xor(p, 8);
        if (n == 0) y[idx_u] = p + Dsk * uv;
        idx_bn += NB2; idx_u += Dd;
    }
}

// ---------- host ----------
static inline size_t al256(size_t x) { return (x + 255) & ~(size_t)255; }

extern "C" void kernel_launch(void* const* d_in, const int* in_sizes, int n_in,
                              void* d_out, int out_size, void* d_ws, size_t ws_size,
                              hipStream_t stream) {
    const float* u       = (const float*)d_in[0];
    const float* log_A   = (const float*)d_in[1];
    const float* D_skip  = (const float*)d_in[2];
    const float* dt_bias = (const float*)d_in[3];
    const float* W_dt    = (const float*)d_in[4];
    const float* b_dt    = (const float*)d_in[5];
    const float* W_B     = (const float*)d_in[6];
    const float* b_B     = (const float*)d_in[7];
    const float* W_C     = (const float*)d_in[8];
    const float* b_C     = (const float*)d_in[9];
    float* y = (float*)d_out;

    // fixed buffers
    const size_t sz_ubf  = al256((size_t)Bb * Ll * Dd * 2);      // 8.4 MB
    const size_t sz_wbc  = al256((size_t)NB2 * Dd * 2);          // 67.1 MB
    const size_t sz_h    = al256((size_t)NCH * Nn * 4);          // 128 KB
    const size_t sz_dtf  = al256((size_t)Bb * Ll * Dd * 4);      // 16.8 MB
    const size_t sz_ucat = al256((size_t)Bb * Ll * KCAT * 2);    // 25.2 MB (overlay)
    const size_t sz_wcat = al256((size_t)Dd * KCAT * 2);         // 6.3 MB (overlay)

    // choose CL: fixed + seg buffers + max(BC chunk, ucat+wcat overlay)
    int CL = 128;
    const int cands[5] = {2048, 1024, 512, 256, 128};
    for (int i = 0; i < 5; ++i) {
        const int c = cands[i];
        const int nseg = c / SL;
        const size_t seg = 3 * al256((size_t)nseg * NCH * Nn * 4);
        const size_t chunk = al256((size_t)2 * c * NB2 * 2);
        const size_t ovl = sz_ucat + sz_wcat;
        const size_t need = sz_ubf + sz_wbc + sz_h + sz_dtf + seg +
                            (chunk > ovl ? chunk : ovl);
        if (need <= ws_size) { CL = c; break; }
    }
    const int NSEG = CL / SL;

    // bump-allocate
    char* p = (char*)d_ws;
    bf16_t* u_bf   = (bf16_t*)p; p += sz_ubf;
    bf16_t* wBC    = (bf16_t*)p; p += sz_wbc;
    float* h_state = (float*)p; p += sz_h;
    float* dt_full = (float*)p; p += sz_dtf;
    const size_t sz_seg1 = al256((size_t)NSEG * NCH * Nn * 4);
    float* pseg    = (float*)p; p += sz_seg1;
    float* hseg    = (float*)p; p += sz_seg1;
    float* hin_arr = (float*)p; p += sz_seg1;
    // chunk region (BC_c) overlaid with u_cat/w_cat (dead after dt GEMM)
    char* chunk0 = p;
    bf16_t* BC_c  = (bf16_t*)chunk0;
    bf16_t* u_cat = (bf16_t*)chunk0;
    bf16_t* w_cat = (bf16_t*)(chunk0 + sz_ucat);

    // prep: u -> {u_bf, u_cat}; W_dt -> w_cat; [W_B;W_C] -> wBC
    build_ucat<<<Bb * Ll * Dd / 4 / 256, 256, 0, stream>>>(u, u_cat, u_bf);
    build_wcat<<<Dd * Dd / 4 / 256, 256, 0, stream>>>(W_dt, w_cat);
    cvt_wbc<<<2048, 256, 0, stream>>>(W_B, W_C, wBC);

    // dt for ALL of L in one MFMA GEMM (64x64 tiles -> 1024 blocks, ~4/CU)
    gemm_dt64<<<dim3(Dd / 64, Bb * Ll / 64), 256, 0, stream>>>(
        u_cat, w_cat, b_dt, dt_bias, dt_full);

    for (int l0 = 0; l0 < Ll; l0 += CL) {
        gemm_bc<<<dim3(NB2 / 128, 2 * CL / 128), 256, 0, stream>>>(
            u_bf, CL, l0, wBC, b_B, b_C, BC_c);
        scan_seg_local<<<dim3(128 * NSEG), 256, 0, stream>>>(
            u, dt_full, BC_c, log_A, pseg, hseg, CL, l0);
        scan_combine<<<dim3(128), 256, 0, stream>>>(
            pseg, hseg, hin_arr, h_state, NSEG, l0);
        scan_seg_final<<<dim3(128 * NSEG), 256, 0, stream>>>(
            u, dt_full, BC_c, log_A, D_skip, hin_arr, y, CL, l0);
    }
}